// Round 16
// baseline (110.169 us; speedup 1.0000x reference)
//
#include <hip/hip_runtime.h>
#include <hip/hip_bf16.h>
#include <hip/hip_cooperative_groups.h>

namespace cg = cooperative_groups;

typedef float f32x4 __attribute__((ext_vector_type(4)));
typedef short short8 __attribute__((ext_vector_type(8)));

#define NTYPES 4
#define GRIDC 256      // cooperative grid: 1 block/CU guaranteed co-resident

// ws layout (bytes):
//   [512,1024)    dump row (pad-node store sink)
//   [2048,2112)   bases[5] (published by fallback scatter; plain stores)
//   [4096,12288)  cnts[][4] per-block histogram slots (fully rewritten/call)
//   [16384,...)   perm[~1567*64] ints (pad slots = -1)
//   [524288,)     W1T bf16 [4][256][128]  W1T[t][hcol][k]
//   [786432,)     W2T bf16 [4][128][256]  W2T[t][ocol][h]

static __device__ __forceinline__ unsigned short f2bf(float f) {
  union { float f; unsigned int u; } v; v.f = f;
  unsigned int u = v.u;
  unsigned int r = u + 0x7FFFu + ((u >> 16) & 1u);   // round-nearest-even
  return (unsigned short)(r >> 16);
}

// packed f32x2 -> bf16x2 (compiler emits v_cvt_pk_bf16_f32; RNE)
static __device__ __forceinline__ unsigned int pkbf(float a, float b) {
  __hip_bfloat162 h = __float22bfloat162_rn(make_float2(a, b));
  union { __hip_bfloat162 h; unsigned int u; } v; v.h = h;
  return v.u;
}

// shared weight-transpose helper (one 64x64 tile per block role)
static __device__ __forceinline__ void prep_tile(int role, int tid,
    const float* __restrict__ W1, const float* __restrict__ W2,
    unsigned short* __restrict__ W1T, unsigned short* __restrict__ W2T,
    unsigned short (*sp)[72]) {
  const int bb = role & 31;
  const int tt = bb >> 3, ti = bb & 7;   // type, tile within type
  const float* src; unsigned short* dst; int scols, tr, tc;
  if (role < 32) { src = W1 + tt * 32768; dst = W1T + tt * 32768; scols = 256; tr = ti >> 2; tc = ti & 3; }
  else           { src = W2 + tt * 32768; dst = W2T + tt * 32768; scols = 128; tr = ti >> 1; tc = ti & 1; }
  const int srows = 32768 / scols;       // dst row length
  const int r0 = tid >> 4, cw = (tid & 15) << 2;
  #pragma unroll
  for (int i = 0; i < 4; ++i) {
    int r = tr * 64 + i * 16 + r0;
    float4 v = *(const float4*)(src + r * scols + tc * 64 + cw);
    sp[i * 16 + r0][cw + 0] = f2bf(v.x);
    sp[i * 16 + r0][cw + 1] = f2bf(v.y);
    sp[i * 16 + r0][cw + 2] = f2bf(v.z);
    sp[i * 16 + r0][cw + 3] = f2bf(v.w);
  }
  __syncthreads();
  #pragma unroll
  for (int i = 0; i < 4; ++i) {
    int orow = i * 16 + r0;
    ushort4 u;
    u.x = sp[cw + 0][orow];
    u.y = sp[cw + 1][orow];
    u.z = sp[cw + 2][orow];
    u.w = sp[cw + 3][orow];
    *(ushort4*)(dst + (tc * 64 + orow) * srows + tr * 64 + cw) = u;
  }
}

// ===================== MLP tile-loop body (R14, proven) =====================
// t: type, lb: local block, nblk: blocks per type, sb0/sb1: segment bounds.
static __device__ __forceinline__ void mlp_body(
    int t, int lb, int nblk, int g0, int g1, int tid,
    const float* __restrict__ X, const int* __restrict__ perm,
    const unsigned short* __restrict__ W1T, const unsigned short* __restrict__ W2T,
    const float* __restrict__ B1, const float* __restrict__ B2,
    float* __restrict__ OUT, float* __restrict__ dump,
    unsigned char* x_lds, unsigned char* h_lds, int (*s_rid)[64]) {
  const int l  = tid & 63, w = tid >> 6;
  const int lo = l & 15,  hi = l >> 4;
  const int nt2 = g1 - g0 - lb;
  if (nt2 <= 0) return;
  const int cnt = (nt2 + nblk - 1) / nblk;

  const int rg = tid >> 5;               // row sub-index 0..7
  const int c4 = (tid & 31) * 4;         // float column 0..124

  if (tid < 64) s_rid[0][tid] = perm[(g0 + lb) * 64 + tid];
  __syncthreads();
  float4 xv[8];
  #pragma unroll
  for (int p = 0; p < 8; ++p) {
    int rd = s_rid[0][p * 8 + rg];
    xv[p] = make_float4(0.f, 0.f, 0.f, 0.f);
    if (rd >= 0) xv[p] = *(const float4*)(X + (size_t)rd * 128 + c4);
  }

  const unsigned short* w1t = W1T + (t << 15);
  const unsigned short* w2t = W2T + (t << 15);
  short8 a1[4][4];
  #pragma unroll
  for (int ks = 0; ks < 4; ++ks)
    #pragma unroll
    for (int m = 0; m < 4; ++m)
      a1[ks][m] = *(const short8*)(w1t + (w * 64 + m * 16 + lo) * 128 + ks * 32 + hi * 8);
  short8 a2[8][2];
  #pragma unroll
  for (int ks = 0; ks < 8; ++ks)
    #pragma unroll
    for (int mo = 0; mo < 2; ++mo)
      a2[ks][mo] = *(const short8*)(w2t + (w * 32 + mo * 16 + lo) * 256 + ks * 32 + hi * 8);
  f32x4 bb1[4], bb2[2];
  #pragma unroll
  for (int m = 0; m < 4; ++m)
    bb1[m] = *(const f32x4*)(B1 + t * 256 + w * 64 + m * 16 + hi * 4);
  #pragma unroll
  for (int mo = 0; mo < 2; ++mo)
    bb2[mo] = *(const f32x4*)(B2 + t * 128 + w * 32 + mo * 16 + hi * 4);

  for (int j = 0; j < cnt; ++j) {
    const int g = g0 + lb + j * nblk;
    const bool hn = (j + 1 < cnt);
    const int cur = j & 1, nxt = cur ^ 1;

    #pragma unroll
    for (int p = 0; p < 8; ++p) {
      int row = p * 8 + rg;
      uint2 u;
      u.x = pkbf(xv[p].x, xv[p].y);
      u.y = pkbf(xv[p].z, xv[p].w);
      int byte = (row * 256 + c4 * 2) ^ ((row & 7) << 4);
      *(uint2*)(x_lds + byte) = u;
    }
    __syncthreads();   // B1: x visible; prev-tile out reads retired

    if (hn && tid < 64) s_rid[nxt][tid] = perm[(g + nblk) * 64 + tid];

    f32x4 acc[4][4];
    #pragma unroll
    for (int m = 0; m < 4; ++m)
      #pragma unroll
      for (int n2 = 0; n2 < 4; ++n2) acc[m][n2] = (f32x4){0.f, 0.f, 0.f, 0.f};
    #pragma unroll
    for (int ks = 0; ks < 4; ++ks) {
      short8 b[4];
      #pragma unroll
      for (int n2 = 0; n2 < 4; ++n2) {
        int row = n2 * 16 + lo;
        int byte = (row * 256 + ks * 64 + hi * 16) ^ ((row & 7) << 4);
        b[n2] = *(const short8*)(x_lds + byte);
      }
      #pragma unroll
      for (int m = 0; m < 4; ++m)
        #pragma unroll
        for (int n2 = 0; n2 < 4; ++n2)
          acc[m][n2] = __builtin_amdgcn_mfma_f32_16x16x32_bf16(a1[ks][m], b[n2], acc[m][n2], 0, 0, 0);
    }

    #pragma unroll
    for (int m = 0; m < 4; ++m) {
      const int hw2 = w * 128 + m * 32 + hi * 8;
      #pragma unroll
      for (int n2 = 0; n2 < 4; ++n2) {
        int node = n2 * 16 + lo;
        uint2 hu;
        hu.x = pkbf(fmaxf(acc[m][n2][0] + bb1[m][0], 0.f),
                    fmaxf(acc[m][n2][1] + bb1[m][1], 0.f));
        hu.y = pkbf(fmaxf(acc[m][n2][2] + bb1[m][2], 0.f),
                    fmaxf(acc[m][n2][3] + bb1[m][3], 0.f));
        int byte = (node * 512 + hw2) ^ ((node & 7) << 4);
        *(uint2*)(h_lds + byte) = hu;
      }
    }
    __syncthreads();   // B2: h visible; x reads retired; s_rid[nxt] visible

    float4 nv[8];
    #pragma unroll
    for (int p = 0; p < 8; ++p) nv[p] = make_float4(0.f, 0.f, 0.f, 0.f);
    if (hn) {
      #pragma unroll
      for (int p = 0; p < 8; ++p) {
        int rd = s_rid[nxt][p * 8 + rg];
        if (rd >= 0) nv[p] = *(const float4*)(X + (size_t)rd * 128 + c4);
      }
    }

    f32x4 acc2[2][4];
    #pragma unroll
    for (int mo = 0; mo < 2; ++mo)
      #pragma unroll
      for (int n2 = 0; n2 < 4; ++n2) acc2[mo][n2] = (f32x4){0.f, 0.f, 0.f, 0.f};
    #pragma unroll
    for (int ks = 0; ks < 8; ++ks) {
      short8 b[4];
      #pragma unroll
      for (int n2 = 0; n2 < 4; ++n2) {
        int node = n2 * 16 + lo;
        int byte = (node * 512 + ks * 64 + hi * 16) ^ ((node & 7) << 4);
        b[n2] = *(const short8*)(h_lds + byte);
      }
      #pragma unroll
      for (int mo = 0; mo < 2; ++mo)
        #pragma unroll
        for (int n2 = 0; n2 < 4; ++n2)
          acc2[mo][n2] = __builtin_amdgcn_mfma_f32_16x16x32_bf16(a2[ks][mo], b[n2], acc2[mo][n2], 0, 0, 0);
    }
    __syncthreads();   // B3a: all h reads done -> safe to overwrite h_lds

    #pragma unroll
    for (int mo = 0; mo < 2; ++mo) {
      const int oc = w * 32 + mo * 16 + hi * 4;
      #pragma unroll
      for (int n2 = 0; n2 < 4; ++n2) {
        int node = n2 * 16 + lo;
        f32x4 o = acc2[mo][n2];
        o[0] += bb2[mo][0]; o[1] += bb2[mo][1];
        o[2] += bb2[mo][2]; o[3] += bb2[mo][3];
        int byte = (node * 512 + oc * 4) ^ ((node & 7) << 4);
        *(f32x4*)(h_lds + byte) = o;
      }
    }
    __syncthreads();   // B3b: out tile visible

    #pragma unroll
    for (int p = 0; p < 8; ++p) {
      int row = p * 8 + rg;
      int rd = s_rid[cur][row];
      f32x4 v = *(const f32x4*)(h_lds + ((row * 512 + c4 * 4) ^ ((row & 7) << 4)));
      float* dst = (rd >= 0) ? (OUT + (size_t)rd * 128 + c4) : (dump + c4);
      *(f32x4*)dst = v;
    }

    #pragma unroll
    for (int p = 0; p < 8; ++p) xv[p] = nv[p];
  }
}

// ===================== cooperative all-in-one (grid 256) =====================
__global__ __launch_bounds__(256, 1) void k_all(
    const float* __restrict__ X, const int* __restrict__ NT,
    const float* __restrict__ W1, const float* __restrict__ B1,
    const float* __restrict__ W2, const float* __restrict__ B2,
    float* __restrict__ OUT, int n,
    int* __restrict__ perm, int* __restrict__ cnts,
    unsigned short* __restrict__ W1T, unsigned short* __restrict__ W2T,
    float* __restrict__ dump) {
  __shared__ __align__(16) unsigned char x_lds[16384];
  __shared__ __align__(16) unsigned char h_lds[32768];   // MLP h/out; prep scratch
  __shared__ int s_rid[2][64];
  __shared__ int lcnt[NTYPES];
  __shared__ int s_tot[NTYPES], s_pre[NTYPES];

  const int tid = threadIdx.x;
  const int bid = blockIdx.x;
  const int l = tid & 63, w = tid >> 6;

  // Phase 1a: per-block histogram (plain stores; no zeroing needed)
  const int span = (n + GRIDC - 1) / GRIDC;
  const int sA = bid * span;
  const int sB = min(n, sA + span);
  if (tid < NTYPES) lcnt[tid] = 0;
  __syncthreads();
  for (int i = sA + tid; i < sB; i += 256) atomicAdd(&lcnt[NT[i]], 1);
  __syncthreads();
  if (tid < NTYPES) cnts[bid * NTYPES + tid] = lcnt[tid];

  // Phase 1b: blocks 0..63 transpose weights
  if (bid < 64)
    prep_tile(bid, tid, W1, W2, W1T, W2T, (unsigned short (*)[72])h_lds);

  cg::this_grid().sync();

  // Phase 2: prefix (wave w = type w; lane l sums blocks l*4..l*4+3) + scatter
  {
    int tot = 0, pre = 0;
    #pragma unroll
    for (int q = 0; q < 4; ++q) {
      int b = l * 4 + q;
      int c = cnts[b * NTYPES + w];
      tot += c;
      pre += (b < bid) ? c : 0;
    }
    #pragma unroll
    for (int off = 32; off; off >>= 1) {
      tot += __shfl_down(tot, off);
      pre += __shfl_down(pre, off);
    }
    if (l == 0) { s_tot[w] = tot; s_pre[w] = pre; }
  }
  __syncthreads();
  int sb[NTYPES + 1];
  sb[0] = 0;
  #pragma unroll
  for (int tau = 0; tau < NTYPES; ++tau)
    sb[tau + 1] = sb[tau] + ((s_tot[tau] + 63) & ~63);

  if (tid < NTYPES) lcnt[tid] = 0;
  __syncthreads();
  for (int i = sA + tid; i < sB; i += 256) {
    int tt = NT[i];
    int r = atomicAdd(&lcnt[tt], 1);
    perm[sb[tt] + s_pre[tt] + r] = i;
  }
  if ((bid & 63) == 0) {                 // block tau*64 pad-fills type tau
    int tau = bid >> 6;
    for (int p = sb[tau] + s_tot[tau] + tid; p < sb[tau + 1]; p += 256)
      perm[p] = -1;
  }

  cg::this_grid().sync();

  // Phase 3: MLP, 64 blocks/type (R11 mapping, R14 body)
  const int t = bid >> 6, lb = bid & 63;
  mlp_body(t, lb, 64, sb[t] >> 6, sb[t + 1] >> 6, tid,
           X, perm, W1T, W2T, B1, B2, OUT, dump, x_lds, h_lds, s_rid);
}

// ===================== fallback chain (3 launches) =====================
__global__ __launch_bounds__(256) void k_hp(
    const float* __restrict__ W1, const float* __restrict__ W2,
    unsigned short* __restrict__ W1T, unsigned short* __restrict__ W2T,
    const int* __restrict__ NT, int n, int* __restrict__ cnts) {
  __shared__ unsigned short sp[64][72];
  __shared__ int lc[NTYPES];
  const int tid = threadIdx.x;
  if (blockIdx.x < 64) {
    prep_tile(blockIdx.x, tid, W1, W2, W1T, W2T, sp);
  } else {
    int hb = blockIdx.x - 64;
    if (tid < NTYPES) lc[tid] = 0;
    __syncthreads();
    int i = hb * 256 + tid;
    if (i < n) atomicAdd(&lc[NT[i]], 1);
    __syncthreads();
    if (tid < NTYPES) cnts[hb * NTYPES + tid] = lc[tid];
  }
}

__global__ __launch_bounds__(256) void k_scatter2(
    const int* __restrict__ NT, int n, const int* __restrict__ cnts, int nbH,
    int* __restrict__ perm, int* __restrict__ bases) {
  __shared__ int s_tot[NTYPES], s_pre[NTYPES], lc[NTYPES];
  const int tid = threadIdx.x;
  const int bid = blockIdx.x;
  const int l = tid & 63, w = tid >> 6;
  {
    int tot = 0, pre = 0;
    for (int b = l; b < nbH; b += 64) {
      int c = cnts[b * NTYPES + w];
      tot += c;
      pre += (b < bid) ? c : 0;
    }
    #pragma unroll
    for (int off = 32; off; off >>= 1) {
      tot += __shfl_down(tot, off);
      pre += __shfl_down(pre, off);
    }
    if (l == 0) { s_tot[w] = tot; s_pre[w] = pre; }
  }
  __syncthreads();
  int sb[NTYPES + 1];
  sb[0] = 0;
  #pragma unroll
  for (int tau = 0; tau < NTYPES; ++tau)
    sb[tau + 1] = sb[tau] + ((s_tot[tau] + 63) & ~63);
  if (bid == 0 && tid <= NTYPES) bases[tid] = sb[tid];
  if (tid < NTYPES) lc[tid] = 0;
  __syncthreads();
  int i = bid * 256 + tid;
  if (i < n) {
    int tt = NT[i];
    int r = atomicAdd(&lc[tt], 1);
    perm[sb[tt] + s_pre[tt] + r] = i;
  }
  if (bid < NTYPES) {
    for (int p = sb[bid] + s_tot[bid] + tid; p < sb[bid + 1]; p += 256)
      perm[p] = -1;
  }
}

__global__ __launch_bounds__(256, 1) void k_mlpw_fb(
    const float* __restrict__ X, const int* __restrict__ perm,
    const int* __restrict__ bases,
    const unsigned short* __restrict__ W1T, const unsigned short* __restrict__ W2T,
    const float* __restrict__ B1, const float* __restrict__ B2,
    float* __restrict__ OUT, float* __restrict__ dump) {
  __shared__ __align__(16) unsigned char x_lds[16384];
  __shared__ __align__(16) unsigned char h_lds[32768];
  __shared__ int s_rid[2][64];
  const int t = blockIdx.x >> 7, lb = blockIdx.x & 127;
  mlp_body(t, lb, 128, bases[t] >> 6, bases[t + 1] >> 6, threadIdx.x,
           X, perm, W1T, W2T, B1, B2, OUT, dump, x_lds, h_lds, s_rid);
}

extern "C" void kernel_launch(void* const* d_in, const int* in_sizes, int n_in,
                              void* d_out, int out_size, void* d_ws, size_t ws_size,
                              hipStream_t stream) {
  const float* X  = (const float*)d_in[0];
  const int*   NT = (const int*)d_in[1];
  const float* W1 = (const float*)d_in[2];
  const float* B1 = (const float*)d_in[3];
  const float* W2 = (const float*)d_in[4];
  const float* B2 = (const float*)d_in[5];
  float* OUT = (float*)d_out;
  int n = in_sizes[1];

  char* ws = (char*)d_ws;
  float* dump = (float*)(ws + 512);
  int* bases = (int*)(ws + 2048);
  int* cnts = (int*)(ws + 4096);
  int* perm = (int*)(ws + 16384);
  unsigned short* W1T = (unsigned short*)(ws + 524288);
  unsigned short* W2T = (unsigned short*)(ws + 786432);

  void* args[13];
  args[0]  = (void*)&X;    args[1]  = (void*)&NT;
  args[2]  = (void*)&W1;   args[3]  = (void*)&B1;
  args[4]  = (void*)&W2;   args[5]  = (void*)&B2;
  args[6]  = (void*)&OUT;  args[7]  = (void*)&n;
  args[8]  = (void*)&perm; args[9]  = (void*)&cnts;
  args[10] = (void*)&W1T;  args[11] = (void*)&W2T;
  args[12] = (void*)&dump;

  hipError_t e = hipLaunchCooperativeKernel((const void*)k_all, dim3(GRIDC),
                                            dim3(256), args, 0, stream);
  if (e != hipSuccess) {
    (void)hipGetLastError();           // clear sticky error
    const int nbH = (n + 255) / 256;   // 391
    k_hp<<<64 + nbH, 256, 0, stream>>>(W1, W2, W1T, W2T, NT, n, cnts);
    k_scatter2<<<nbH, 256, 0, stream>>>(NT, n, cnts, nbH, perm, bases);
    k_mlpw_fb<<<512, 256, 0, stream>>>(X, perm, bases, W1T, W2T, B1, B2, OUT, dump);
  }
}

// Round 17
// 49.249 us; speedup vs baseline: 2.2370x; 2.2370x over previous
//
#include <hip/hip_runtime.h>
#include <hip/hip_bf16.h>

typedef float f32x4 __attribute__((ext_vector_type(4)));
typedef short short8 __attribute__((ext_vector_type(8)));

#define NTYPES 4

// ws layout (bytes):
//   [512,1024)    dump row (pad-node store sink)
//   [2048,2112)   bases[5] (published by k_scatter2 block 0; plain stores)
//   [4096,12288)  cnts[][4] per-block histogram slots (fully rewritten/call)
//   [16384,...)   perm[~1567*64] ints (pad slots = -1)
//   [524288,)     W1T bf16 [4][256][128]  W1T[t][hcol][k]
//   [786432,)     W2T bf16 [4][128][256]  W2T[t][ocol][h]

static __device__ __forceinline__ unsigned short f2bf(float f) {
  union { float f; unsigned int u; } v; v.f = f;
  unsigned int u = v.u;
  unsigned int r = u + 0x7FFFu + ((u >> 16) & 1u);   // round-nearest-even
  return (unsigned short)(r >> 16);
}

// packed f32x2 -> bf16x2 (compiler emits v_cvt_pk_bf16_f32; RNE)
static __device__ __forceinline__ unsigned int pkbf(float a, float b) {
  __hip_bfloat162 h = __float22bfloat162_rn(make_float2(a, b));
  union { __hip_bfloat162 h; unsigned int u; } v; v.h = h;
  return v.u;
}

// weight-transpose helper (one 64x64 tile per block role) — proven R8+
static __device__ __forceinline__ void prep_tile(int role, int tid,
    const float* __restrict__ W1, const float* __restrict__ W2,
    unsigned short* __restrict__ W1T, unsigned short* __restrict__ W2T,
    unsigned short (*sp)[72]) {
  const int bb = role & 31;
  const int tt = bb >> 3, ti = bb & 7;   // type, tile within type
  const float* src; unsigned short* dst; int scols, tr, tc;
  if (role < 32) { src = W1 + tt * 32768; dst = W1T + tt * 32768; scols = 256; tr = ti >> 2; tc = ti & 3; }
  else           { src = W2 + tt * 32768; dst = W2T + tt * 32768; scols = 128; tr = ti >> 1; tc = ti & 1; }
  const int srows = 32768 / scols;       // dst row length
  const int r0 = tid >> 4, cw = (tid & 15) << 2;
  #pragma unroll
  for (int i = 0; i < 4; ++i) {
    int r = tr * 64 + i * 16 + r0;
    float4 v = *(const float4*)(src + r * scols + tc * 64 + cw);
    sp[i * 16 + r0][cw + 0] = f2bf(v.x);
    sp[i * 16 + r0][cw + 1] = f2bf(v.y);
    sp[i * 16 + r0][cw + 2] = f2bf(v.z);
    sp[i * 16 + r0][cw + 3] = f2bf(v.w);
  }
  __syncthreads();
  #pragma unroll
  for (int i = 0; i < 4; ++i) {
    int orow = i * 16 + r0;
    ushort4 u;
    u.x = sp[cw + 0][orow];
    u.y = sp[cw + 1][orow];
    u.z = sp[cw + 2][orow];
    u.w = sp[cw + 3][orow];
    *(ushort4*)(dst + (tc * 64 + orow) * srows + tr * 64 + cw) = u;
  }
}

// ===================== MLP tile-loop body (R14, measured 43.5us) ============
static __device__ __forceinline__ void mlp_body(
    int t, int lb, int nblk, int g0, int g1, int tid,
    const float* __restrict__ X, const int* __restrict__ perm,
    const unsigned short* __restrict__ W1T, const unsigned short* __restrict__ W2T,
    const float* __restrict__ B1, const float* __restrict__ B2,
    float* __restrict__ OUT, float* __restrict__ dump,
    unsigned char* x_lds, unsigned char* h_lds, int (*s_rid)[64]) {
  const int l  = tid & 63, w = tid >> 6;
  const int lo = l & 15,  hi = l >> 4;
  const int nt2 = g1 - g0 - lb;
  if (nt2 <= 0) return;
  const int cnt = (nt2 + nblk - 1) / nblk;

  const int rg = tid >> 5;               // row sub-index 0..7
  const int c4 = (tid & 31) * 4;         // float column 0..124

  if (tid < 64) s_rid[0][tid] = perm[(g0 + lb) * 64 + tid];
  __syncthreads();
  float4 xv[8];
  #pragma unroll
  for (int p = 0; p < 8; ++p) {
    int rd = s_rid[0][p * 8 + rg];
    xv[p] = make_float4(0.f, 0.f, 0.f, 0.f);
    if (rd >= 0) xv[p] = *(const float4*)(X + (size_t)rd * 128 + c4);
  }

  const unsigned short* w1t = W1T + (t << 15);
  const unsigned short* w2t = W2T + (t << 15);
  short8 a1[4][4];
  #pragma unroll
  for (int ks = 0; ks < 4; ++ks)
    #pragma unroll
    for (int m = 0; m < 4; ++m)
      a1[ks][m] = *(const short8*)(w1t + (w * 64 + m * 16 + lo) * 128 + ks * 32 + hi * 8);
  short8 a2[8][2];
  #pragma unroll
  for (int ks = 0; ks < 8; ++ks)
    #pragma unroll
    for (int mo = 0; mo < 2; ++mo)
      a2[ks][mo] = *(const short8*)(w2t + (w * 32 + mo * 16 + lo) * 256 + ks * 32 + hi * 8);
  f32x4 bb1[4], bb2[2];
  #pragma unroll
  for (int m = 0; m < 4; ++m)
    bb1[m] = *(const f32x4*)(B1 + t * 256 + w * 64 + m * 16 + hi * 4);
  #pragma unroll
  for (int mo = 0; mo < 2; ++mo)
    bb2[mo] = *(const f32x4*)(B2 + t * 128 + w * 32 + mo * 16 + hi * 4);

  for (int j = 0; j < cnt; ++j) {
    const int g = g0 + lb + j * nblk;
    const bool hn = (j + 1 < cnt);
    const int cur = j & 1, nxt = cur ^ 1;

    #pragma unroll
    for (int p = 0; p < 8; ++p) {
      int row = p * 8 + rg;
      uint2 u;
      u.x = pkbf(xv[p].x, xv[p].y);
      u.y = pkbf(xv[p].z, xv[p].w);
      int byte = (row * 256 + c4 * 2) ^ ((row & 7) << 4);
      *(uint2*)(x_lds + byte) = u;
    }
    __syncthreads();   // B1: x visible; prev-tile out reads retired

    if (hn && tid < 64) s_rid[nxt][tid] = perm[(g + nblk) * 64 + tid];

    f32x4 acc[4][4];
    #pragma unroll
    for (int m = 0; m < 4; ++m)
      #pragma unroll
      for (int n2 = 0; n2 < 4; ++n2) acc[m][n2] = (f32x4){0.f, 0.f, 0.f, 0.f};
    #pragma unroll
    for (int ks = 0; ks < 4; ++ks) {
      short8 b[4];
      #pragma unroll
      for (int n2 = 0; n2 < 4; ++n2) {
        int row = n2 * 16 + lo;
        int byte = (row * 256 + ks * 64 + hi * 16) ^ ((row & 7) << 4);
        b[n2] = *(const short8*)(x_lds + byte);
      }
      #pragma unroll
      for (int m = 0; m < 4; ++m)
        #pragma unroll
        for (int n2 = 0; n2 < 4; ++n2)
          acc[m][n2] = __builtin_amdgcn_mfma_f32_16x16x32_bf16(a1[ks][m], b[n2], acc[m][n2], 0, 0, 0);
    }

    #pragma unroll
    for (int m = 0; m < 4; ++m) {
      const int hw2 = w * 128 + m * 32 + hi * 8;
      #pragma unroll
      for (int n2 = 0; n2 < 4; ++n2) {
        int node = n2 * 16 + lo;
        uint2 hu;
        hu.x = pkbf(fmaxf(acc[m][n2][0] + bb1[m][0], 0.f),
                    fmaxf(acc[m][n2][1] + bb1[m][1], 0.f));
        hu.y = pkbf(fmaxf(acc[m][n2][2] + bb1[m][2], 0.f),
                    fmaxf(acc[m][n2][3] + bb1[m][3], 0.f));
        int byte = (node * 512 + hw2) ^ ((node & 7) << 4);
        *(uint2*)(h_lds + byte) = hu;
      }
    }
    __syncthreads();   // B2: h visible; x reads retired; s_rid[nxt] visible

    float4 nv[8];
    #pragma unroll
    for (int p = 0; p < 8; ++p) nv[p] = make_float4(0.f, 0.f, 0.f, 0.f);
    if (hn) {
      #pragma unroll
      for (int p = 0; p < 8; ++p) {
        int rd = s_rid[nxt][p * 8 + rg];
        if (rd >= 0) nv[p] = *(const float4*)(X + (size_t)rd * 128 + c4);
      }
    }

    f32x4 acc2[2][4];
    #pragma unroll
    for (int mo = 0; mo < 2; ++mo)
      #pragma unroll
      for (int n2 = 0; n2 < 4; ++n2) acc2[mo][n2] = (f32x4){0.f, 0.f, 0.f, 0.f};
    #pragma unroll
    for (int ks = 0; ks < 8; ++ks) {
      short8 b[4];
      #pragma unroll
      for (int n2 = 0; n2 < 4; ++n2) {
        int node = n2 * 16 + lo;
        int byte = (node * 512 + ks * 64 + hi * 16) ^ ((node & 7) << 4);
        b[n2] = *(const short8*)(h_lds + byte);
      }
      #pragma unroll
      for (int mo = 0; mo < 2; ++mo)
        #pragma unroll
        for (int n2 = 0; n2 < 4; ++n2)
          acc2[mo][n2] = __builtin_amdgcn_mfma_f32_16x16x32_bf16(a2[ks][mo], b[n2], acc2[mo][n2], 0, 0, 0);
    }
    __syncthreads();   // B3a: all h reads done -> safe to overwrite h_lds

    #pragma unroll
    for (int mo = 0; mo < 2; ++mo) {
      const int oc = w * 32 + mo * 16 + hi * 4;
      #pragma unroll
      for (int n2 = 0; n2 < 4; ++n2) {
        int node = n2 * 16 + lo;
        f32x4 o = acc2[mo][n2];
        o[0] += bb2[mo][0]; o[1] += bb2[mo][1];
        o[2] += bb2[mo][2]; o[3] += bb2[mo][3];
        int byte = (node * 512 + oc * 4) ^ ((node & 7) << 4);
        *(f32x4*)(h_lds + byte) = o;
      }
    }
    __syncthreads();   // B3b: out tile visible

    #pragma unroll
    for (int p = 0; p < 8; ++p) {
      int row = p * 8 + rg;
      int rd = s_rid[cur][row];
      f32x4 v = *(const f32x4*)(h_lds + ((row * 512 + c4 * 4) ^ ((row & 7) << 4)));
      float* dst = (rd >= 0) ? (OUT + (size_t)rd * 128 + c4) : (dump + c4);
      *(f32x4*)dst = v;
    }

    #pragma unroll
    for (int p = 0; p < 8; ++p) xv[p] = nv[p];
  }
}

// ============ launch 1: weight transpose (blocks 0-63) + histogram ==========
__global__ __launch_bounds__(256) void k_hp(
    const float* __restrict__ W1, const float* __restrict__ W2,
    unsigned short* __restrict__ W1T, unsigned short* __restrict__ W2T,
    const int* __restrict__ NT, int n, int* __restrict__ cnts) {
  __shared__ unsigned short sp[64][72];
  __shared__ int lc[NTYPES];
  const int tid = threadIdx.x;
  if (blockIdx.x < 64) {
    prep_tile(blockIdx.x, tid, W1, W2, W1T, W2T, sp);
  } else {
    int hb = blockIdx.x - 64;
    if (tid < NTYPES) lc[tid] = 0;
    __syncthreads();
    int i = hb * 256 + tid;
    if (i < n) atomicAdd(&lc[NT[i]], 1);
    __syncthreads();
    if (tid < NTYPES) cnts[hb * NTYPES + tid] = lc[tid];
  }
}

// ============ launch 2: deterministic scatter from cnts + base publish ======
__global__ __launch_bounds__(256) void k_scatter2(
    const int* __restrict__ NT, int n, const int* __restrict__ cnts, int nbH,
    int* __restrict__ perm, int* __restrict__ bases) {
  __shared__ int s_tot[NTYPES], s_pre[NTYPES], lc[NTYPES];
  const int tid = threadIdx.x;
  const int bid = blockIdx.x;
  const int l = tid & 63, w = tid >> 6;
  {
    int tot = 0, pre = 0;
    for (int b = l; b < nbH; b += 64) {
      int c = cnts[b * NTYPES + w];
      tot += c;
      pre += (b < bid) ? c : 0;
    }
    #pragma unroll
    for (int off = 32; off; off >>= 1) {
      tot += __shfl_down(tot, off);
      pre += __shfl_down(pre, off);
    }
    if (l == 0) { s_tot[w] = tot; s_pre[w] = pre; }
  }
  __syncthreads();
  int sb[NTYPES + 1];
  sb[0] = 0;
  #pragma unroll
  for (int tau = 0; tau < NTYPES; ++tau)
    sb[tau + 1] = sb[tau] + ((s_tot[tau] + 63) & ~63);   // pad segments to 64
  if (bid == 0 && tid <= NTYPES) bases[tid] = sb[tid];
  if (tid < NTYPES) lc[tid] = 0;
  __syncthreads();
  int i = bid * 256 + tid;
  if (i < n) {
    int tt = NT[i];
    int r = atomicAdd(&lc[tt], 1);
    perm[sb[tt] + s_pre[tt] + r] = i;
  }
  if (bid < NTYPES) {
    for (int p = sb[bid] + s_tot[bid] + tid; p < sb[bid + 1]; p += 256)
      perm[p] = -1;
  }
}

// ============ launch 3: weights-stationary MLP (R14 geometry) ===============
// __launch_bounds__(256,1): VGPR cap 512 — lower caps collapse to spill
// (R6/R10: +70-100MB scratch FETCH). Sync: __syncthreads() only (R12 race).
__global__ __launch_bounds__(256, 1) void k_mlpw_fb(
    const float* __restrict__ X, const int* __restrict__ perm,
    const int* __restrict__ bases,
    const unsigned short* __restrict__ W1T, const unsigned short* __restrict__ W2T,
    const float* __restrict__ B1, const float* __restrict__ B2,
    float* __restrict__ OUT, float* __restrict__ dump) {
  __shared__ __align__(16) unsigned char x_lds[16384];
  __shared__ __align__(16) unsigned char h_lds[32768];
  __shared__ int s_rid[2][64];
  const int t = blockIdx.x >> 7, lb = blockIdx.x & 127;
  mlp_body(t, lb, 128, bases[t] >> 6, bases[t + 1] >> 6, threadIdx.x,
           X, perm, W1T, W2T, B1, B2, OUT, dump, x_lds, h_lds, s_rid);
}

extern "C" void kernel_launch(void* const* d_in, const int* in_sizes, int n_in,
                              void* d_out, int out_size, void* d_ws, size_t ws_size,
                              hipStream_t stream) {
  const float* X  = (const float*)d_in[0];
  const int*   NT = (const int*)d_in[1];
  const float* W1 = (const float*)d_in[2];
  const float* B1 = (const float*)d_in[3];
  const float* W2 = (const float*)d_in[4];
  const float* B2 = (const float*)d_in[5];
  float* OUT = (float*)d_out;
  int n = in_sizes[1];

  char* ws = (char*)d_ws;
  float* dump = (float*)(ws + 512);
  int* bases = (int*)(ws + 2048);
  int* cnts = (int*)(ws + 4096);
  int* perm = (int*)(ws + 16384);
  unsigned short* W1T = (unsigned short*)(ws + 524288);
  unsigned short* W2T = (unsigned short*)(ws + 786432);

  const int nbH = (n + 255) / 256;   // 391
  k_hp<<<64 + nbH, 256, 0, stream>>>(W1, W2, W1T, W2T, NT, n, cnts);
  k_scatter2<<<nbH, 256, 0, stream>>>(NT, n, cnts, nbH, perm, bases);
  k_mlpw_fb<<<512, 256, 0, stream>>>(X, perm, bases, W1T, W2T, B1, B2, OUT, dump);
}